// Round 5
// baseline (115.151 us; speedup 1.0000x reference)
//
#include <hip/hip_runtime.h>

#define N_TOKENS   65536
#define TOKS_PER_BLK 128
#define MAIN_BLOCKS (N_TOKENS / TOKS_PER_BLK + 100)   // 612 (padding: <=100 partial buckets)
#define ORD_SIZE    (MAIN_BLOCKS * TOKS_PER_BLK)      // 78336

// ---- ws layout (float offsets) ----
#define WS_W    0                         // 32*128        = 4096
#define WS_M2   4096                      // 100*32*128    = 409600
#define WS_G1T  413696                    // 10000*32      = 320000
#define WS_CNT  733696                    // 128 ints
#define WS_CUR  733824                    // 128 ints
#define WS_ORD  733952                    // ORD_SIZE ints
#define WS_NEED ((size_t)(733952 + ORD_SIZE) * 4)     // ~3.25 MB

#define FMA4(A, S, V) do { A.x = fmaf((S), (V).x, A.x); A.y = fmaf((S), (V).y, A.y); \
                           A.z = fmaf((S), (V).z, A.z); A.w = fmaf((S), (V).w, A.w); } while (0)

// ---------------------------------------------------------------------------
// K1: W[32][128] = fold(core3, core4, core5)   (verified in round 4)
// ---------------------------------------------------------------------------
__global__ void build_w(const float* __restrict__ c3, const float* __restrict__ c4,
                        const float* __restrict__ c5, float* __restrict__ W) {
    int t = blockIdx.x * blockDim.x + threadIdx.x;
    if (t >= 32 * 128) return;
    int r = t >> 7;
    int j = t & 127;
    int p  = j >> 5;
    int m1 = (j >> 2) & 7;
    int v  = j & 3;
    const float* c3row = c3 + (r * 4 + p) * 16;
    float acc = 0.f;
#pragma unroll
    for (int m2 = 0; m2 < 8; ++m2) {
        float t1 = 0.f;
#pragma unroll
        for (int q = 0; q < 16; ++q)
            t1 += c3row[q] * c4[q * 64 + m1 * 8 + m2];
        acc += t1 * c5[m2 * 4 + v];
    }
    W[r * 128 + j] = acc;
}

// ---------------------------------------------------------------------------
// K2: M2[i2][r][j] = sum_s c2[r,i2,s] * W[s,j]      grid 400 x 256
// blockIdx: i2 = b>>2, r-quarter = b&3.  thread: r = rq*8 + (t>>5), j4 = t&31
// ---------------------------------------------------------------------------
__global__ void build_m2(const float* __restrict__ c2, const float* __restrict__ W,
                         float* __restrict__ M2) {
    const int i2 = blockIdx.x >> 2;
    const int rq = blockIdx.x & 3;
    const int j4 = threadIdx.x & 31;
    const int r  = rq * 8 + (threadIdx.x >> 5);
    const float* c2row = c2 + r * 3200 + i2 * 32;
    const float4* W4 = (const float4*)W;
    float4 acc = {0.f, 0.f, 0.f, 0.f};
#pragma unroll
    for (int s = 0; s < 32; ++s) {
        const float cv = c2row[s];
        const float4 wv = W4[s * 32 + j4];
        FMA4(acc, cv, wv);
    }
    ((float4*)(M2 + (i2 * 32 + r) * 128))[j4] = acc;
}

// ---------------------------------------------------------------------------
// K3: fused  (a) G1T[pair][s] = sum_r c0[i0,r]*c1[r,i1,s]  for pair = i0*100+i1
//            (b) histogram of i2 into counts[100]
// grid 1250 + 64 = 1314 x 256
// ---------------------------------------------------------------------------
__global__ void g1t_hist(const int* __restrict__ idx, const float* __restrict__ c0,
                         const float* __restrict__ c1, float* __restrict__ G1T,
                         int* __restrict__ counts) {
    __shared__ int lh[128];
    const int b = blockIdx.x, t = threadIdx.x;
    if (b < 1250) {
        const int g = t >> 5, s = t & 31;
        const int pair = b * 8 + g;
        const int i0 = pair / 100;
        const int i1 = pair - i0 * 100;
        const float4* a4 = (const float4*)(c0 + i0 * 32);
        const float* c1p = c1 + i1 * 32 + s;
        float acc = 0.f;
#pragma unroll
        for (int r4 = 0; r4 < 8; ++r4) {
            const float4 a = a4[r4];
            acc = fmaf(a.x, c1p[(r4 * 4 + 0) * 3200], acc);
            acc = fmaf(a.y, c1p[(r4 * 4 + 1) * 3200], acc);
            acc = fmaf(a.z, c1p[(r4 * 4 + 2) * 3200], acc);
            acc = fmaf(a.w, c1p[(r4 * 4 + 3) * 3200], acc);
        }
        G1T[pair * 32 + s] = acc;
    } else {
        const int hb = b - 1250;
        if (t < 128) lh[t] = 0;
        __syncthreads();
#pragma unroll
        for (int k = 0; k < 4; ++k) {
            const int n = hb * 1024 + k * 256 + t;
            const int i2 = idx[n] % 100;
            atomicAdd(&lh[i2], 1);
        }
        __syncthreads();
        if (t < 100) atomicAdd(&counts[t], lh[t]);
    }
}

// ---------------------------------------------------------------------------
// K4: padded exclusive scan: cursor[k] = start of bucket k, padded to 128
// ---------------------------------------------------------------------------
__global__ void scan_pad(const int* __restrict__ counts, int* __restrict__ cursor) {
    if (threadIdx.x == 0) {
        int acc = 0;
        for (int k = 0; k < 100; ++k) {
            cursor[k] = acc;
            acc += ((counts[k] + (TOKS_PER_BLK - 1)) / TOKS_PER_BLK) * TOKS_PER_BLK;
        }
    }
}

// ---------------------------------------------------------------------------
// K5: scatter token ids into bucket order (intra-bucket order irrelevant)
// ---------------------------------------------------------------------------
__global__ void scatter(const int* __restrict__ idx, int* __restrict__ cursor,
                        int* __restrict__ order) {
    const int b = blockIdx.x, t = threadIdx.x;
#pragma unroll
    for (int k = 0; k < 4; ++k) {
        const int n = b * 1024 + k * 256 + t;
        const int i2 = idx[n] % 100;
        const int pos = atomicAdd(&cursor[i2], 1);
        order[pos] = n;
    }
}

// ---------------------------------------------------------------------------
// K6: main  out[n][j] = sum_r G1T[iv/100][r] * M2[iv%100][r][j]
// grid MAIN_BLOCKS x 256.  Per block: one i2 bucket chunk of <=128 tokens.
// Thread tile: 8 tokens x 8 cols, g1 transposed in LDS (pad +4), M2 slice in LDS.
// ---------------------------------------------------------------------------
__global__ __launch_bounds__(256) void tt_main(
    const int* __restrict__ idx, const int* __restrict__ order,
    const float* __restrict__ G1T, const float* __restrict__ M2,
    float* __restrict__ out) {
    __shared__ float M2l[32 * 128];        // 16 KB
    __shared__ float g1l[32][132];         // 16.9 KB (pad 4 keeps b128 alignment, spreads banks)
    __shared__ int   toks[TOKS_PER_BLK];

    const int t = threadIdx.x;
    const int base = blockIdx.x * TOKS_PER_BLK;
    const int n0 = order[base];
    if (n0 < 0) return;                    // unused padded block
    const int i2v = idx[n0] % 100;

    // stage M2 slice (4096 floats)
    {
        const float4* src = (const float4*)(M2 + i2v * 4096);
        float4* dst = (float4*)M2l;
#pragma unroll
        for (int i = 0; i < 4; ++i) dst[t + i * 256] = src[t + i * 256];
    }
    // stage g1 transposed: 2 threads per token, 16 r each
    {
        const int tk = t >> 1, half = t & 1;
        const int n = order[base + tk];
        float4 x0 = {0,0,0,0}, x1 = {0,0,0,0}, x2 = {0,0,0,0}, x3 = {0,0,0,0};
        if (n >= 0) {
            const int pair = idx[n] / 100;      // i0*100 + i1
            const float4* g = (const float4*)(G1T + pair * 32 + half * 16);
            x0 = g[0]; x1 = g[1]; x2 = g[2]; x3 = g[3];
        }
        const int rb = half * 16;
        g1l[rb +  0][tk] = x0.x; g1l[rb +  1][tk] = x0.y; g1l[rb +  2][tk] = x0.z; g1l[rb +  3][tk] = x0.w;
        g1l[rb +  4][tk] = x1.x; g1l[rb +  5][tk] = x1.y; g1l[rb +  6][tk] = x1.z; g1l[rb +  7][tk] = x1.w;
        g1l[rb +  8][tk] = x2.x; g1l[rb +  9][tk] = x2.y; g1l[rb + 10][tk] = x2.z; g1l[rb + 11][tk] = x2.w;
        g1l[rb + 12][tk] = x3.x; g1l[rb + 13][tk] = x3.y; g1l[rb + 14][tk] = x3.z; g1l[rb + 15][tk] = x3.w;
        if (t < TOKS_PER_BLK) toks[t] = order[base + t];
    }
    __syncthreads();

    const int tg = t >> 4;   // token group (8 tokens)
    const int cg = t & 15;   // col group (8 cols)
    float4 acc[8][2];
#pragma unroll
    for (int k = 0; k < 8; ++k) {
        acc[k][0] = {0.f, 0.f, 0.f, 0.f};
        acc[k][1] = {0.f, 0.f, 0.f, 0.f};
    }

#pragma unroll 8
    for (int r = 0; r < 32; ++r) {
        const float* g1r = &g1l[r][tg * 8];
        const float4 ga = *(const float4*)g1r;
        const float4 gb = *(const float4*)(g1r + 4);
        const float4* m2r = (const float4*)(M2l + r * 128 + cg * 8);
        const float4 m0 = m2r[0];
        const float4 m1 = m2r[1];
        FMA4(acc[0][0], ga.x, m0); FMA4(acc[0][1], ga.x, m1);
        FMA4(acc[1][0], ga.y, m0); FMA4(acc[1][1], ga.y, m1);
        FMA4(acc[2][0], ga.z, m0); FMA4(acc[2][1], ga.z, m1);
        FMA4(acc[3][0], ga.w, m0); FMA4(acc[3][1], ga.w, m1);
        FMA4(acc[4][0], gb.x, m0); FMA4(acc[4][1], gb.x, m1);
        FMA4(acc[5][0], gb.y, m0); FMA4(acc[5][1], gb.y, m1);
        FMA4(acc[6][0], gb.z, m0); FMA4(acc[6][1], gb.z, m1);
        FMA4(acc[7][0], gb.w, m0); FMA4(acc[7][1], gb.w, m1);
    }

#pragma unroll
    for (int k = 0; k < 8; ++k) {
        const int n = toks[tg * 8 + k];
        if (n >= 0) {
            float4* o = (float4*)(out + (size_t)n * 128 + cg * 8);
            o[0] = acc[k][0];
            o[1] = acc[k][1];
        }
    }
}

// ---------------------------------------------------------------------------
// Fallback (round-4 verified path) if ws is too small for the tables.
// ---------------------------------------------------------------------------
__global__ __launch_bounds__(256, 4) void tt_embed_fb(
    const int* __restrict__ idx, const float* __restrict__ c0,
    const float* __restrict__ c1, const float* __restrict__ c2,
    const float* __restrict__ Wg, float* __restrict__ out) {
    __shared__ float Wl[32 * 128];
    __shared__ float g2l[8][32];
    const int t = threadIdx.x;
    {
        const float4* Wg4 = (const float4*)Wg;
        float4* Wl4 = (float4*)Wl;
#pragma unroll
        for (int i = 0; i < 4; ++i) Wl4[t + i * 256] = Wg4[t + i * 256];
    }
    __syncthreads();
    const int tt = t >> 5, s = t & 31;
    const int blockBase = blockIdx.x * 32;
    for (int round = 0; round < 4; ++round) {
        const int n = blockBase + round * 8 + tt;
        const int iv = idx[n];
        const int i0 = iv / 10000;
        const int rem = iv - i0 * 10000;
        const int i1 = rem / 100;
        const int i2 = rem - i1 * 100;
        const float4* c0r4 = (const float4*)(c0 + i0 * 32);
        const float* c1p = c1 + i1 * 32 + s;
        float g1 = 0.f;
#pragma unroll
        for (int r4 = 0; r4 < 8; ++r4) {
            float4 a = c0r4[r4];
            g1 += a.x * c1p[(r4 * 4 + 0) * 3200];
            g1 += a.y * c1p[(r4 * 4 + 1) * 3200];
            g1 += a.z * c1p[(r4 * 4 + 2) * 3200];
            g1 += a.w * c1p[(r4 * 4 + 3) * 3200];
        }
        const float* c2p = c2 + i2 * 32 + s;
        float g2 = 0.f;
#pragma unroll
        for (int r = 0; r < 32; ++r) {
            float g1r = __shfl(g1, r, 32);
            g2 += g1r * c2p[r * 3200];
        }
        g2l[tt][s] = g2;
        __syncthreads();
        float4 acc = {0.f, 0.f, 0.f, 0.f};
        const float4* Wl4 = (const float4*)Wl;
#pragma unroll
        for (int r = 0; r < 32; ++r) {
            const float g = g2l[tt][r];
            const float4 w = Wl4[r * 32 + s];
            acc.x += g * w.x; acc.y += g * w.y; acc.z += g * w.z; acc.w += g * w.w;
        }
        float4* outp = (float4*)(out + (size_t)n * 128);
        outp[s] = acc;
        __syncthreads();
    }
}

// ---------------------------------------------------------------------------
extern "C" void kernel_launch(void* const* d_in, const int* in_sizes, int n_in,
                              void* d_out, int out_size, void* d_ws, size_t ws_size,
                              hipStream_t stream) {
    const int*   idx = (const int*)d_in[0];
    const float* c0  = (const float*)d_in[1];
    const float* c1  = (const float*)d_in[2];
    const float* c2  = (const float*)d_in[3];
    const float* c3  = (const float*)d_in[4];
    const float* c4  = (const float*)d_in[5];
    const float* c5  = (const float*)d_in[6];
    float* out = (float*)d_out;
    float* ws  = (float*)d_ws;

    float* W   = ws + WS_W;

    if (ws_size >= WS_NEED) {
        float* M2  = ws + WS_M2;
        float* G1T = ws + WS_G1T;
        int* counts = (int*)(ws + WS_CNT);
        int* cursor = (int*)(ws + WS_CUR);
        int* order  = (int*)(ws + WS_ORD);

        hipMemsetAsync(counts, 0, 128 * sizeof(int), stream);
        hipMemsetAsync(order, 0xFF, ORD_SIZE * sizeof(int), stream);

        hipLaunchKernelGGL(build_w,  dim3(16),   dim3(256), 0, stream, c3, c4, c5, W);
        hipLaunchKernelGGL(build_m2, dim3(400),  dim3(256), 0, stream, c2, W, M2);
        hipLaunchKernelGGL(g1t_hist, dim3(1314), dim3(256), 0, stream, idx, c0, c1, G1T, counts);
        hipLaunchKernelGGL(scan_pad, dim3(1),    dim3(64),  0, stream, counts, cursor);
        hipLaunchKernelGGL(scatter,  dim3(64),   dim3(256), 0, stream, idx, cursor, order);
        hipLaunchKernelGGL(tt_main,  dim3(MAIN_BLOCKS), dim3(256), 0, stream,
                           idx, order, G1T, M2, out);
    } else {
        // fallback: round-4 verified path (needs only 16 KB ws)
        hipLaunchKernelGGL(build_w, dim3(16), dim3(256), 0, stream, c3, c4, c5, W);
        hipLaunchKernelGGL(tt_embed_fb, dim3(N_TOKENS / 32), dim3(256), 0, stream,
                           idx, c0, c1, c2, W, out);
    }
}

// Round 6
// 48.169 us; speedup vs baseline: 2.3905x; 2.3905x over previous
//
#include <hip/hip_runtime.h>

#define N_TOKENS   65536
#define TOKS_PER_BLK 128
#define MAIN_BLOCKS (N_TOKENS / TOKS_PER_BLK + 100)   // 612 (<=100 partial buckets)
#define ORD_SIZE    (MAIN_BLOCKS * TOKS_PER_BLK)      // 78336
#define PADI 32                                        // 128-B stride for contended counters

// ---- ws layout (float offsets) ----
#define WS_W    0                         // 32*128        = 4096
#define WS_M2   4096                      // 100*32*128    = 409600
#define WS_G1T  413696                    // 10000*32      = 320000
#define WS_CNT  733696                    // 100*PADI ints = 3200
#define WS_CUR  736896                    // 100*PADI ints = 3200
#define WS_ORD  740096                    // ORD_SIZE ints
#define WS_NEED ((size_t)(740096 + ORD_SIZE) * 4)     // ~3.27 MB

#define FMA4(A, S, V) do { A.x = fmaf((S), (V).x, A.x); A.y = fmaf((S), (V).y, A.y); \
                           A.z = fmaf((S), (V).z, A.z); A.w = fmaf((S), (V).w, A.w); } while (0)

// ---------------------------------------------------------------------------
// K1: W[32][128] = fold(core3, core4, core5)   (verified round 4)
// ---------------------------------------------------------------------------
__global__ void build_w(const float* __restrict__ c3, const float* __restrict__ c4,
                        const float* __restrict__ c5, float* __restrict__ W) {
    int t = blockIdx.x * blockDim.x + threadIdx.x;
    if (t >= 32 * 128) return;
    int r = t >> 7;
    int j = t & 127;
    int p  = j >> 5;
    int m1 = (j >> 2) & 7;
    int v  = j & 3;
    const float* c3row = c3 + (r * 4 + p) * 16;
    float acc = 0.f;
#pragma unroll
    for (int m2 = 0; m2 < 8; ++m2) {
        float t1 = 0.f;
#pragma unroll
        for (int q = 0; q < 16; ++q)
            t1 += c3row[q] * c4[q * 64 + m1 * 8 + m2];
        acc += t1 * c5[m2 * 4 + v];
    }
    W[r * 128 + j] = acc;
}

// ---------------------------------------------------------------------------
// K2: M2[i2][r][j] = sum_s c2[r,i2,s] * W[s,j]      grid 400 x 256
// ---------------------------------------------------------------------------
__global__ void build_m2(const float* __restrict__ c2, const float* __restrict__ W,
                         float* __restrict__ M2) {
    const int i2 = blockIdx.x >> 2;
    const int rq = blockIdx.x & 3;
    const int j4 = threadIdx.x & 31;
    const int r  = rq * 8 + (threadIdx.x >> 5);
    const float* c2row = c2 + r * 3200 + i2 * 32;
    const float4* W4 = (const float4*)W;
    float4 acc = {0.f, 0.f, 0.f, 0.f};
#pragma unroll
    for (int s = 0; s < 32; ++s) {
        const float cv = c2row[s];
        const float4 wv = W4[s * 32 + j4];
        FMA4(acc, cv, wv);
    }
    ((float4*)(M2 + (i2 * 32 + r) * 128))[j4] = acc;
}

// ---------------------------------------------------------------------------
// K3: fused  (a) G1T[pair][s] = sum_r c0[i0,r]*c1[r,i1,s]
//            (b) histogram of i2 into padded counts (LDS-aggregated)
// grid 1250 + 64 = 1314 x 256
// ---------------------------------------------------------------------------
__global__ void g1t_hist(const int* __restrict__ idx, const float* __restrict__ c0,
                         const float* __restrict__ c1, float* __restrict__ G1T,
                         int* __restrict__ counts) {
    __shared__ int lh[128];
    const int b = blockIdx.x, t = threadIdx.x;
    if (b < 1250) {
        const int g = t >> 5, s = t & 31;
        const int pair = b * 8 + g;
        const int i0 = pair / 100;
        const int i1 = pair - i0 * 100;
        const float4* a4 = (const float4*)(c0 + i0 * 32);
        const float* c1p = c1 + i1 * 32 + s;
        float acc = 0.f;
#pragma unroll
        for (int r4 = 0; r4 < 8; ++r4) {
            const float4 a = a4[r4];
            acc = fmaf(a.x, c1p[(r4 * 4 + 0) * 3200], acc);
            acc = fmaf(a.y, c1p[(r4 * 4 + 1) * 3200], acc);
            acc = fmaf(a.z, c1p[(r4 * 4 + 2) * 3200], acc);
            acc = fmaf(a.w, c1p[(r4 * 4 + 3) * 3200], acc);
        }
        G1T[pair * 32 + s] = acc;
    } else {
        const int hb = b - 1250;
        if (t < 128) lh[t] = 0;
        __syncthreads();
#pragma unroll
        for (int k = 0; k < 4; ++k) {
            const int n = hb * 1024 + k * 256 + t;
            const int i2 = idx[n] % 100;
            atomicAdd(&lh[i2], 1);
        }
        __syncthreads();
        if (t < 100 && lh[t] > 0) atomicAdd(&counts[t * PADI], lh[t]);
    }
}

// ---------------------------------------------------------------------------
// K4: padded exclusive scan (one wave, 2 elems/lane, shfl_up)
// cursor[k*PADI] = start of bucket k, each bucket padded to 128
// ---------------------------------------------------------------------------
__global__ void scan_pad(const int* __restrict__ counts, int* __restrict__ cursor) {
    const int lane = threadIdx.x;                 // 0..63
    const int e0 = 2 * lane, e1 = 2 * lane + 1;
    int c0 = (e0 < 100) ? counts[e0 * PADI] : 0;
    int c1 = (e1 < 100) ? counts[e1 * PADI] : 0;
    c0 = ((c0 + TOKS_PER_BLK - 1) / TOKS_PER_BLK) * TOKS_PER_BLK;
    c1 = ((c1 + TOKS_PER_BLK - 1) / TOKS_PER_BLK) * TOKS_PER_BLK;
    const int pair = c0 + c1;
    int incl = pair;
#pragma unroll
    for (int d = 1; d < 64; d <<= 1) {
        const int v = __shfl_up(incl, d, 64);
        if (lane >= d) incl += v;
    }
    const int base = incl - pair;                 // exclusive
    if (e0 < 100) cursor[e0 * PADI] = base;
    if (e1 < 100) cursor[e1 * PADI] = base + c0;
}

// ---------------------------------------------------------------------------
// K5: scatter, block-aggregated: LDS ranks + 1 padded global atomic per
// (block, bucket).  grid 64 x 256, 4 tokens/thread.
// ---------------------------------------------------------------------------
__global__ __launch_bounds__(256) void scatter(const int* __restrict__ idx,
                                               int* __restrict__ cursor,
                                               int* __restrict__ order) {
    __shared__ int lh[100];
    __shared__ int lbase[100];
    const int t = threadIdx.x;
    if (t < 100) lh[t] = 0;
    __syncthreads();
    int rank[4], bkt[4], tok[4];
#pragma unroll
    for (int k = 0; k < 4; ++k) {
        const int n = blockIdx.x * 1024 + k * 256 + t;
        const int i2 = idx[n] % 100;
        tok[k] = n;
        bkt[k] = i2;
        rank[k] = atomicAdd(&lh[i2], 1);          // LDS atomic: intra-block rank
    }
    __syncthreads();
    if (t < 100 && lh[t] > 0) lbase[t] = atomicAdd(&cursor[t * PADI], lh[t]);
    __syncthreads();
#pragma unroll
    for (int k = 0; k < 4; ++k)
        order[lbase[bkt[k]] + rank[k]] = tok[k];
}

// ---------------------------------------------------------------------------
// K6: main  out[n][j] = sum_r G1T[iv/100][r] * M2[iv%100][r][j]
// Per block: one i2-bucket chunk of <=128 tokens.  8tok x 8col per thread;
// cols split {cg*4, 64+cg*4} so the two b128 LDS reads sweep all 32 banks.
// ---------------------------------------------------------------------------
__global__ __launch_bounds__(256) void tt_main(
    const int* __restrict__ idx, const int* __restrict__ order,
    const float* __restrict__ G1T, const float* __restrict__ M2,
    float* __restrict__ out) {
    __shared__ float M2l[32 * 128];        // 16 KB
    __shared__ float g1l[32][132];         // pad 4
    __shared__ int   toks[TOKS_PER_BLK];

    const int t = threadIdx.x;
    const int base = blockIdx.x * TOKS_PER_BLK;
    const int n0 = order[base];
    if (n0 < 0) return;                    // padded block
    const int i2v = idx[n0] % 100;

    {
        const float4* src = (const float4*)(M2 + i2v * 4096);
        float4* dst = (float4*)M2l;
#pragma unroll
        for (int i = 0; i < 4; ++i) dst[t + i * 256] = src[t + i * 256];
    }
    {
        const int tk = t >> 1, half = t & 1;
        const int n = order[base + tk];
        float4 x0 = {0,0,0,0}, x1 = {0,0,0,0}, x2 = {0,0,0,0}, x3 = {0,0,0,0};
        if (n >= 0) {
            const int pair = idx[n] / 100;
            const float4* g = (const float4*)(G1T + pair * 32 + half * 16);
            x0 = g[0]; x1 = g[1]; x2 = g[2]; x3 = g[3];
        }
        const int rb = half * 16;
        g1l[rb +  0][tk] = x0.x; g1l[rb +  1][tk] = x0.y; g1l[rb +  2][tk] = x0.z; g1l[rb +  3][tk] = x0.w;
        g1l[rb +  4][tk] = x1.x; g1l[rb +  5][tk] = x1.y; g1l[rb +  6][tk] = x1.z; g1l[rb +  7][tk] = x1.w;
        g1l[rb +  8][tk] = x2.x; g1l[rb +  9][tk] = x2.y; g1l[rb + 10][tk] = x2.z; g1l[rb + 11][tk] = x2.w;
        g1l[rb + 12][tk] = x3.x; g1l[rb + 13][tk] = x3.y; g1l[rb + 14][tk] = x3.z; g1l[rb + 15][tk] = x3.w;
        if (t < TOKS_PER_BLK) toks[t] = order[base + t];
    }
    __syncthreads();

    const int tg = t >> 4;   // token group (8 tokens)
    const int cg = t & 15;   // col group: cols {cg*4..+3} and {64+cg*4..+3}
    float4 acc[8][2];
#pragma unroll
    for (int k = 0; k < 8; ++k) {
        acc[k][0] = {0.f, 0.f, 0.f, 0.f};
        acc[k][1] = {0.f, 0.f, 0.f, 0.f};
    }

#pragma unroll 8
    for (int r = 0; r < 32; ++r) {
        const float* g1r = &g1l[r][tg * 8];
        const float4 ga = *(const float4*)g1r;
        const float4 gb = *(const float4*)(g1r + 4);
        const float4 m0 = *(const float4*)(M2l + r * 128 + cg * 4);
        const float4 m1 = *(const float4*)(M2l + r * 128 + 64 + cg * 4);
        FMA4(acc[0][0], ga.x, m0); FMA4(acc[0][1], ga.x, m1);
        FMA4(acc[1][0], ga.y, m0); FMA4(acc[1][1], ga.y, m1);
        FMA4(acc[2][0], ga.z, m0); FMA4(acc[2][1], ga.z, m1);
        FMA4(acc[3][0], ga.w, m0); FMA4(acc[3][1], ga.w, m1);
        FMA4(acc[4][0], gb.x, m0); FMA4(acc[4][1], gb.x, m1);
        FMA4(acc[5][0], gb.y, m0); FMA4(acc[5][1], gb.y, m1);
        FMA4(acc[6][0], gb.z, m0); FMA4(acc[6][1], gb.z, m1);
        FMA4(acc[7][0], gb.w, m0); FMA4(acc[7][1], gb.w, m1);
    }

#pragma unroll
    for (int k = 0; k < 8; ++k) {
        const int n = toks[tg * 8 + k];
        if (n >= 0) {
            float* o = out + (size_t)n * 128;
            *(float4*)(o + cg * 4)      = acc[k][0];
            *(float4*)(o + 64 + cg * 4) = acc[k][1];
        }
    }
}

// ---------------------------------------------------------------------------
// Fallback (round-4 verified path) if ws is too small.
// ---------------------------------------------------------------------------
__global__ __launch_bounds__(256, 4) void tt_embed_fb(
    const int* __restrict__ idx, const float* __restrict__ c0,
    const float* __restrict__ c1, const float* __restrict__ c2,
    const float* __restrict__ Wg, float* __restrict__ out) {
    __shared__ float Wl[32 * 128];
    __shared__ float g2l[8][32];
    const int t = threadIdx.x;
    {
        const float4* Wg4 = (const float4*)Wg;
        float4* Wl4 = (float4*)Wl;
#pragma unroll
        for (int i = 0; i < 4; ++i) Wl4[t + i * 256] = Wg4[t + i * 256];
    }
    __syncthreads();
    const int tt = t >> 5, s = t & 31;
    const int blockBase = blockIdx.x * 32;
    for (int round = 0; round < 4; ++round) {
        const int n = blockBase + round * 8 + tt;
        const int iv = idx[n];
        const int i0 = iv / 10000;
        const int rem = iv - i0 * 10000;
        const int i1 = rem / 100;
        const int i2 = rem - i1 * 100;
        const float4* c0r4 = (const float4*)(c0 + i0 * 32);
        const float* c1p = c1 + i1 * 32 + s;
        float g1 = 0.f;
#pragma unroll
        for (int r4 = 0; r4 < 8; ++r4) {
            float4 a = c0r4[r4];
            g1 += a.x * c1p[(r4 * 4 + 0) * 3200];
            g1 += a.y * c1p[(r4 * 4 + 1) * 3200];
            g1 += a.z * c1p[(r4 * 4 + 2) * 3200];
            g1 += a.w * c1p[(r4 * 4 + 3) * 3200];
        }
        const float* c2p = c2 + i2 * 32 + s;
        float g2 = 0.f;
#pragma unroll
        for (int r = 0; r < 32; ++r) {
            float g1r = __shfl(g1, r, 32);
            g2 += g1r * c2p[r * 3200];
        }
        g2l[tt][s] = g2;
        __syncthreads();
        float4 acc = {0.f, 0.f, 0.f, 0.f};
        const float4* Wl4 = (const float4*)Wl;
#pragma unroll
        for (int r = 0; r < 32; ++r) {
            const float g = g2l[tt][r];
            const float4 w = Wl4[r * 32 + s];
            acc.x += g * w.x; acc.y += g * w.y; acc.z += g * w.z; acc.w += g * w.w;
        }
        float4* outp = (float4*)(out + (size_t)n * 128);
        outp[s] = acc;
        __syncthreads();
    }
}

// ---------------------------------------------------------------------------
extern "C" void kernel_launch(void* const* d_in, const int* in_sizes, int n_in,
                              void* d_out, int out_size, void* d_ws, size_t ws_size,
                              hipStream_t stream) {
    const int*   idx = (const int*)d_in[0];
    const float* c0  = (const float*)d_in[1];
    const float* c1  = (const float*)d_in[2];
    const float* c2  = (const float*)d_in[3];
    const float* c3  = (const float*)d_in[4];
    const float* c4  = (const float*)d_in[5];
    const float* c5  = (const float*)d_in[6];
    float* out = (float*)d_out;
    float* ws  = (float*)d_ws;

    float* W = ws + WS_W;

    if (ws_size >= WS_NEED) {
        float* M2  = ws + WS_M2;
        float* G1T = ws + WS_G1T;
        int* counts = (int*)(ws + WS_CNT);
        int* cursor = (int*)(ws + WS_CUR);
        int* order  = (int*)(ws + WS_ORD);

        hipMemsetAsync(counts, 0, 100 * PADI * sizeof(int), stream);
        hipMemsetAsync(order, 0xFF, ORD_SIZE * sizeof(int), stream);

        hipLaunchKernelGGL(build_w,  dim3(16),   dim3(256), 0, stream, c3, c4, c5, W);
        hipLaunchKernelGGL(build_m2, dim3(400),  dim3(256), 0, stream, c2, W, M2);
        hipLaunchKernelGGL(g1t_hist, dim3(1314), dim3(256), 0, stream, idx, c0, c1, G1T, counts);
        hipLaunchKernelGGL(scan_pad, dim3(1),    dim3(64),  0, stream, counts, cursor);
        hipLaunchKernelGGL(scatter,  dim3(64),   dim3(256), 0, stream, idx, cursor, order);
        hipLaunchKernelGGL(tt_main,  dim3(MAIN_BLOCKS), dim3(256), 0, stream,
                           idx, order, G1T, M2, out);
    } else {
        hipLaunchKernelGGL(build_w, dim3(16), dim3(256), 0, stream, c3, c4, c5, W);
        hipLaunchKernelGGL(tt_embed_fb, dim3(N_TOKENS / 32), dim3(256), 0, stream,
                           idx, c0, c1, c2, W, out);
    }
}

// Round 7
// 45.985 us; speedup vs baseline: 2.5041x; 1.0475x over previous
//
#include <hip/hip_runtime.h>

#define N_TOKENS   65536
#define TOKS_PER_BLK 128
#define MAIN_BLOCKS (N_TOKENS / TOKS_PER_BLK + 100)   // 612 (<=100 partial buckets)
#define ORD_SIZE    (MAIN_BLOCKS * TOKS_PER_BLK)      // 78336
#define PADI 32                                        // 128-B stride for contended counters

// ---- ws layout (float offsets) ----
#define WS_W    0                         // 32*128        = 4096
#define WS_M2   4096                      // 100*32*128    = 409600
#define WS_G1T  413696                    // 10000*32      = 320000
#define WS_CNT  733696                    // 100*PADI ints = 3200
#define WS_CUR  736896                    // 100*PADI ints = 3200
#define WS_ORD  740096                    // ORD_SIZE ints
#define WS_NEED ((size_t)(740096 + ORD_SIZE) * 4)     // ~3.27 MB

#define FMA4(A, S, V) do { A.x = fmaf((S), (V).x, A.x); A.y = fmaf((S), (V).y, A.y); \
                           A.z = fmaf((S), (V).z, A.z); A.w = fmaf((S), (V).w, A.w); } while (0)

// ---------------------------------------------------------------------------
// K0: init workspace counters (replaces two hipMemsetAsync nodes: the rocclr
// fill kernel for the 313 KB order buffer was 42 us of pure launch latency).
// grid 80 x 256 = 20480 threads.
// ---------------------------------------------------------------------------
__global__ void init_ws(int* __restrict__ counts, int* __restrict__ order) {
    const int t = blockIdx.x * blockDim.x + threadIdx.x;
    if (t < 100 * PADI) counts[t] = 0;
#pragma unroll
    for (int k = 0; k < 4; ++k) {
        const int i = t + k * 20480;
        if (i < ORD_SIZE) order[i] = -1;
    }
}

// ---------------------------------------------------------------------------
// K1: W[32][128] = fold(core3, core4, core5)   (verified round 4)
// ---------------------------------------------------------------------------
__global__ void build_w(const float* __restrict__ c3, const float* __restrict__ c4,
                        const float* __restrict__ c5, float* __restrict__ W) {
    int t = blockIdx.x * blockDim.x + threadIdx.x;
    if (t >= 32 * 128) return;
    int r = t >> 7;
    int j = t & 127;
    int p  = j >> 5;
    int m1 = (j >> 2) & 7;
    int v  = j & 3;
    const float* c3row = c3 + (r * 4 + p) * 16;
    float acc = 0.f;
#pragma unroll
    for (int m2 = 0; m2 < 8; ++m2) {
        float t1 = 0.f;
#pragma unroll
        for (int q = 0; q < 16; ++q)
            t1 += c3row[q] * c4[q * 64 + m1 * 8 + m2];
        acc += t1 * c5[m2 * 4 + v];
    }
    W[r * 128 + j] = acc;
}

// ---------------------------------------------------------------------------
// K2: M2[i2][r][j] = sum_s c2[r,i2,s] * W[s,j]      grid 400 x 256
// ---------------------------------------------------------------------------
__global__ void build_m2(const float* __restrict__ c2, const float* __restrict__ W,
                         float* __restrict__ M2) {
    const int i2 = blockIdx.x >> 2;
    const int rq = blockIdx.x & 3;
    const int j4 = threadIdx.x & 31;
    const int r  = rq * 8 + (threadIdx.x >> 5);
    const float* c2row = c2 + r * 3200 + i2 * 32;
    const float4* W4 = (const float4*)W;
    float4 acc = {0.f, 0.f, 0.f, 0.f};
#pragma unroll
    for (int s = 0; s < 32; ++s) {
        const float cv = c2row[s];
        const float4 wv = W4[s * 32 + j4];
        FMA4(acc, cv, wv);
    }
    ((float4*)(M2 + (i2 * 32 + r) * 128))[j4] = acc;
}

// ---------------------------------------------------------------------------
// K3: fused  (a) G1T[pair][s] = sum_r c0[i0,r]*c1[r,i1,s]
//            (b) histogram of i2 into padded counts (LDS-aggregated)
// grid 1250 + 64 = 1314 x 256
// ---------------------------------------------------------------------------
__global__ void g1t_hist(const int* __restrict__ idx, const float* __restrict__ c0,
                         const float* __restrict__ c1, float* __restrict__ G1T,
                         int* __restrict__ counts) {
    __shared__ int lh[128];
    const int b = blockIdx.x, t = threadIdx.x;
    if (b < 1250) {
        const int g = t >> 5, s = t & 31;
        const int pair = b * 8 + g;
        const int i0 = pair / 100;
        const int i1 = pair - i0 * 100;
        const float4* a4 = (const float4*)(c0 + i0 * 32);
        const float* c1p = c1 + i1 * 32 + s;
        float acc = 0.f;
#pragma unroll
        for (int r4 = 0; r4 < 8; ++r4) {
            const float4 a = a4[r4];
            acc = fmaf(a.x, c1p[(r4 * 4 + 0) * 3200], acc);
            acc = fmaf(a.y, c1p[(r4 * 4 + 1) * 3200], acc);
            acc = fmaf(a.z, c1p[(r4 * 4 + 2) * 3200], acc);
            acc = fmaf(a.w, c1p[(r4 * 4 + 3) * 3200], acc);
        }
        G1T[pair * 32 + s] = acc;
    } else {
        const int hb = b - 1250;
        if (t < 128) lh[t] = 0;
        __syncthreads();
#pragma unroll
        for (int k = 0; k < 4; ++k) {
            const int n = hb * 1024 + k * 256 + t;
            const int i2 = idx[n] % 100;
            atomicAdd(&lh[i2], 1);
        }
        __syncthreads();
        if (t < 100 && lh[t] > 0) atomicAdd(&counts[t * PADI], lh[t]);
    }
}

// ---------------------------------------------------------------------------
// K4: padded exclusive scan (one wave, 2 elems/lane, shfl_up)
// ---------------------------------------------------------------------------
__global__ void scan_pad(const int* __restrict__ counts, int* __restrict__ cursor) {
    const int lane = threadIdx.x;                 // 0..63
    const int e0 = 2 * lane, e1 = 2 * lane + 1;
    int c0 = (e0 < 100) ? counts[e0 * PADI] : 0;
    int c1 = (e1 < 100) ? counts[e1 * PADI] : 0;
    c0 = ((c0 + TOKS_PER_BLK - 1) / TOKS_PER_BLK) * TOKS_PER_BLK;
    c1 = ((c1 + TOKS_PER_BLK - 1) / TOKS_PER_BLK) * TOKS_PER_BLK;
    const int pair = c0 + c1;
    int incl = pair;
#pragma unroll
    for (int d = 1; d < 64; d <<= 1) {
        const int v = __shfl_up(incl, d, 64);
        if (lane >= d) incl += v;
    }
    const int base = incl - pair;                 // exclusive
    if (e0 < 100) cursor[e0 * PADI] = base;
    if (e1 < 100) cursor[e1 * PADI] = base + c0;
}

// ---------------------------------------------------------------------------
// K5: scatter, block-aggregated: LDS ranks + 1 padded global atomic per
// (block, bucket).  grid 64 x 256, 4 tokens/thread.
// ---------------------------------------------------------------------------
__global__ __launch_bounds__(256) void scatter(const int* __restrict__ idx,
                                               int* __restrict__ cursor,
                                               int* __restrict__ order) {
    __shared__ int lh[100];
    __shared__ int lbase[100];
    const int t = threadIdx.x;
    if (t < 100) lh[t] = 0;
    __syncthreads();
    int rank[4], bkt[4], tok[4];
#pragma unroll
    for (int k = 0; k < 4; ++k) {
        const int n = blockIdx.x * 1024 + k * 256 + t;
        const int i2 = idx[n] % 100;
        tok[k] = n;
        bkt[k] = i2;
        rank[k] = atomicAdd(&lh[i2], 1);          // LDS atomic: intra-block rank
    }
    __syncthreads();
    if (t < 100 && lh[t] > 0) lbase[t] = atomicAdd(&cursor[t * PADI], lh[t]);
    __syncthreads();
#pragma unroll
    for (int k = 0; k < 4; ++k)
        order[lbase[bkt[k]] + rank[k]] = tok[k];
}

// ---------------------------------------------------------------------------
// K6: main  out[n][j] = sum_r G1T[iv/100][r] * M2[iv%100][r][j]
// Per block: one i2-bucket chunk of <=128 tokens.  8tok x 8col per thread;
// cols split {cg*4, 64+cg*4} so the two b128 LDS reads sweep all 32 banks.
// ---------------------------------------------------------------------------
__global__ __launch_bounds__(256) void tt_main(
    const int* __restrict__ idx, const int* __restrict__ order,
    const float* __restrict__ G1T, const float* __restrict__ M2,
    float* __restrict__ out) {
    __shared__ float M2l[32 * 128];        // 16 KB
    __shared__ float g1l[32][132];         // pad 4
    __shared__ int   toks[TOKS_PER_BLK];

    const int t = threadIdx.x;
    const int base = blockIdx.x * TOKS_PER_BLK;
    const int n0 = order[base];
    if (n0 < 0) return;                    // padded block
    const int i2v = idx[n0] % 100;

    {
        const float4* src = (const float4*)(M2 + i2v * 4096);
        float4* dst = (float4*)M2l;
#pragma unroll
        for (int i = 0; i < 4; ++i) dst[t + i * 256] = src[t + i * 256];
    }
    {
        const int tk = t >> 1, half = t & 1;
        const int n = order[base + tk];
        float4 x0 = {0,0,0,0}, x1 = {0,0,0,0}, x2 = {0,0,0,0}, x3 = {0,0,0,0};
        if (n >= 0) {
            const int pair = idx[n] / 100;
            const float4* g = (const float4*)(G1T + pair * 32 + half * 16);
            x0 = g[0]; x1 = g[1]; x2 = g[2]; x3 = g[3];
        }
        const int rb = half * 16;
        g1l[rb +  0][tk] = x0.x; g1l[rb +  1][tk] = x0.y; g1l[rb +  2][tk] = x0.z; g1l[rb +  3][tk] = x0.w;
        g1l[rb +  4][tk] = x1.x; g1l[rb +  5][tk] = x1.y; g1l[rb +  6][tk] = x1.z; g1l[rb +  7][tk] = x1.w;
        g1l[rb +  8][tk] = x2.x; g1l[rb +  9][tk] = x2.y; g1l[rb + 10][tk] = x2.z; g1l[rb + 11][tk] = x2.w;
        g1l[rb + 12][tk] = x3.x; g1l[rb + 13][tk] = x3.y; g1l[rb + 14][tk] = x3.z; g1l[rb + 15][tk] = x3.w;
        if (t < TOKS_PER_BLK) toks[t] = order[base + t];
    }
    __syncthreads();

    const int tg = t >> 4;   // token group (8 tokens)
    const int cg = t & 15;   // col group: cols {cg*4..+3} and {64+cg*4..+3}
    float4 acc[8][2];
#pragma unroll
    for (int k = 0; k < 8; ++k) {
        acc[k][0] = {0.f, 0.f, 0.f, 0.f};
        acc[k][1] = {0.f, 0.f, 0.f, 0.f};
    }

#pragma unroll 8
    for (int r = 0; r < 32; ++r) {
        const float* g1r = &g1l[r][tg * 8];
        const float4 ga = *(const float4*)g1r;
        const float4 gb = *(const float4*)(g1r + 4);
        const float4 m0 = *(const float4*)(M2l + r * 128 + cg * 4);
        const float4 m1 = *(const float4*)(M2l + r * 128 + 64 + cg * 4);
        FMA4(acc[0][0], ga.x, m0); FMA4(acc[0][1], ga.x, m1);
        FMA4(acc[1][0], ga.y, m0); FMA4(acc[1][1], ga.y, m1);
        FMA4(acc[2][0], ga.z, m0); FMA4(acc[2][1], ga.z, m1);
        FMA4(acc[3][0], ga.w, m0); FMA4(acc[3][1], ga.w, m1);
        FMA4(acc[4][0], gb.x, m0); FMA4(acc[4][1], gb.x, m1);
        FMA4(acc[5][0], gb.y, m0); FMA4(acc[5][1], gb.y, m1);
        FMA4(acc[6][0], gb.z, m0); FMA4(acc[6][1], gb.z, m1);
        FMA4(acc[7][0], gb.w, m0); FMA4(acc[7][1], gb.w, m1);
    }

#pragma unroll
    for (int k = 0; k < 8; ++k) {
        const int n = toks[tg * 8 + k];
        if (n >= 0) {
            float* o = out + (size_t)n * 128;
            *(float4*)(o + cg * 4)      = acc[k][0];
            *(float4*)(o + 64 + cg * 4) = acc[k][1];
        }
    }
}

// ---------------------------------------------------------------------------
// Fallback (round-4 verified path) if ws is too small.
// ---------------------------------------------------------------------------
__global__ __launch_bounds__(256, 4) void tt_embed_fb(
    const int* __restrict__ idx, const float* __restrict__ c0,
    const float* __restrict__ c1, const float* __restrict__ c2,
    const float* __restrict__ Wg, float* __restrict__ out) {
    __shared__ float Wl[32 * 128];
    __shared__ float g2l[8][32];
    const int t = threadIdx.x;
    {
        const float4* Wg4 = (const float4*)Wg;
        float4* Wl4 = (float4*)Wl;
#pragma unroll
        for (int i = 0; i < 4; ++i) Wl4[t + i * 256] = Wg4[t + i * 256];
    }
    __syncthreads();
    const int tt = t >> 5, s = t & 31;
    const int blockBase = blockIdx.x * 32;
    for (int round = 0; round < 4; ++round) {
        const int n = blockBase + round * 8 + tt;
        const int iv = idx[n];
        const int i0 = iv / 10000;
        const int rem = iv - i0 * 10000;
        const int i1 = rem / 100;
        const int i2 = rem - i1 * 100;
        const float4* c0r4 = (const float4*)(c0 + i0 * 32);
        const float* c1p = c1 + i1 * 32 + s;
        float g1 = 0.f;
#pragma unroll
        for (int r4 = 0; r4 < 8; ++r4) {
            float4 a = c0r4[r4];
            g1 += a.x * c1p[(r4 * 4 + 0) * 3200];
            g1 += a.y * c1p[(r4 * 4 + 1) * 3200];
            g1 += a.z * c1p[(r4 * 4 + 2) * 3200];
            g1 += a.w * c1p[(r4 * 4 + 3) * 3200];
        }
        const float* c2p = c2 + i2 * 32 + s;
        float g2 = 0.f;
#pragma unroll
        for (int r = 0; r < 32; ++r) {
            float g1r = __shfl(g1, r, 32);
            g2 += g1r * c2p[r * 3200];
        }
        g2l[tt][s] = g2;
        __syncthreads();
        float4 acc = {0.f, 0.f, 0.f, 0.f};
        const float4* Wl4 = (const float4*)Wl;
#pragma unroll
        for (int r = 0; r < 32; ++r) {
            const float g = g2l[tt][r];
            const float4 w = Wl4[r * 32 + s];
            acc.x += g * w.x; acc.y += g * w.y; acc.z += g * w.z; acc.w += g * w.w;
        }
        float4* outp = (float4*)(out + (size_t)n * 128);
        outp[s] = acc;
        __syncthreads();
    }
}

// ---------------------------------------------------------------------------
extern "C" void kernel_launch(void* const* d_in, const int* in_sizes, int n_in,
                              void* d_out, int out_size, void* d_ws, size_t ws_size,
                              hipStream_t stream) {
    const int*   idx = (const int*)d_in[0];
    const float* c0  = (const float*)d_in[1];
    const float* c1  = (const float*)d_in[2];
    const float* c2  = (const float*)d_in[3];
    const float* c3  = (const float*)d_in[4];
    const float* c4  = (const float*)d_in[5];
    const float* c5  = (const float*)d_in[6];
    float* out = (float*)d_out;
    float* ws  = (float*)d_ws;

    float* W = ws + WS_W;

    if (ws_size >= WS_NEED) {
        float* M2  = ws + WS_M2;
        float* G1T = ws + WS_G1T;
        int* counts = (int*)(ws + WS_CNT);
        int* cursor = (int*)(ws + WS_CUR);
        int* order  = (int*)(ws + WS_ORD);

        hipLaunchKernelGGL(init_ws,  dim3(80),   dim3(256), 0, stream, counts, order);
        hipLaunchKernelGGL(build_w,  dim3(16),   dim3(256), 0, stream, c3, c4, c5, W);
        hipLaunchKernelGGL(build_m2, dim3(400),  dim3(256), 0, stream, c2, W, M2);
        hipLaunchKernelGGL(g1t_hist, dim3(1314), dim3(256), 0, stream, idx, c0, c1, G1T, counts);
        hipLaunchKernelGGL(scan_pad, dim3(1),    dim3(64),  0, stream, counts, cursor);
        hipLaunchKernelGGL(scatter,  dim3(64),   dim3(256), 0, stream, idx, cursor, order);
        hipLaunchKernelGGL(tt_main,  dim3(MAIN_BLOCKS), dim3(256), 0, stream,
                           idx, order, G1T, M2, out);
    } else {
        hipLaunchKernelGGL(build_w, dim3(16), dim3(256), 0, stream, c3, c4, c5, W);
        hipLaunchKernelGGL(tt_embed_fb, dim3(N_TOKENS / 32), dim3(256), 0, stream,
                           idx, c0, c1, c2, W, out);
    }
}

// Round 8
// 34.224 us; speedup vs baseline: 3.3647x; 1.3437x over previous
//
#include <hip/hip_runtime.h>

#define N_TOKENS   65536
#define TOKS_PER_BLK 128
#define MAIN_BLOCKS (N_TOKENS / TOKS_PER_BLK + 100)   // 612 (<=100 partial buckets)
#define ORD_SIZE    (MAIN_BLOCKS * TOKS_PER_BLK)      // 78336
#define NB_M2   100
#define NB_G1T  1250
#define NB_HIST 64
#define PREP_BLOCKS (NB_M2 + NB_G1T + NB_HIST)        // 1414

// ---- ws layout (float offsets) ----
#define WS_M2   0                          // 100*32*128 = 409600
#define WS_G1T  409600                     // 10000*32   = 320000
#define WS_CNT  729600                     // 64*128 ints = 8192
#define WS_ORD  737792                     // ORD_SIZE ints
#define WS_NEED ((size_t)(737792 + ORD_SIZE) * 4)     // ~3.27 MB

#define FMA4(A, S, V) do { A.x = fmaf((S), (V).x, A.x); A.y = fmaf((S), (V).y, A.y); \
                           A.z = fmaf((S), (V).z, A.z); A.w = fmaf((S), (V).w, A.w); } while (0)

// ---------------------------------------------------------------------------
// K1 "prep" — role-split by blockIdx.x:
//   [0,100):        per-i2 W (in LDS) + M2[i2] = c2[:,i2,:] @ W
//   [100,1350):     G1T[pair][s] = sum_r c0[i0,r]*c1[r,i1,s]   (8 pairs/block)
//   [1350,1414):    per-block hist of i2 -> cnt[hb][0..127] (plain stores)
// ---------------------------------------------------------------------------
__global__ __launch_bounds__(256) void prep(
    const int* __restrict__ idx,
    const float* __restrict__ c0, const float* __restrict__ c1,
    const float* __restrict__ c2, const float* __restrict__ c3,
    const float* __restrict__ c4, const float* __restrict__ c5,
    float* __restrict__ M2, float* __restrict__ G1T, int* __restrict__ cnt) {
    __shared__ float smem[8768];           // ~34.3 KB, carved per role
    const int b = blockIdx.x, t = threadIdx.x;

    if (b < NB_M2) {
        const int i2 = b;
        float* c4l = smem;                 // 1024
        float* c5l = smem + 1024;          // 32
        float* t45 = smem + 1056;          // 512
        float* c3l = smem + 1568;          // 2048
        float* Wl  = smem + 3616;          // 4096
        float* c2l = smem + 7712;          // 1024
        // stage c3,c4,c5,c2-slice
        *(float4*)(c4l + t * 4) = *(const float4*)(c4 + t * 4);
        if (t < 8) *(float4*)(c5l + t * 4) = *(const float4*)(c5 + t * 4);
        *(float4*)(c3l + t * 8)     = *(const float4*)(c3 + t * 8);
        *(float4*)(c3l + t * 8 + 4) = *(const float4*)(c3 + t * 8 + 4);
        {
            const int r = t >> 3, s4 = t & 7;
            *(float4*)(c2l + r * 32 + s4 * 4) =
                *(const float4*)(c2 + r * 3200 + i2 * 32 + s4 * 4);
        }
        __syncthreads();
        // T45[q][u] = sum_m2 c4[q,m1,m2]*c5[m2,v]   (u = m1*4+v)
#pragma unroll
        for (int k = 0; k < 2; ++k) {
            const int e = t + k * 256;     // 512 entries
            const int q = e >> 5, u = e & 31;
            const int m1 = u >> 2, v = u & 3;
            float acc = 0.f;
#pragma unroll
            for (int m2 = 0; m2 < 8; ++m2)
                acc = fmaf(c4l[q * 64 + m1 * 8 + m2], c5l[m2 * 4 + v], acc);
            t45[e] = acc;
        }
        __syncthreads();
        // W[r][j] = sum_q c3[r,p,q]*T45[q][u]   (j = p*32+u)
#pragma unroll 4
        for (int k = 0; k < 16; ++k) {
            const int e = t + k * 256;     // 4096 entries
            const int r = e >> 7, j = e & 127;
            const int p = j >> 5, u = j & 31;
            const float* c3row = c3l + (r * 4 + p) * 16;
            float acc = 0.f;
#pragma unroll
            for (int q = 0; q < 16; ++q)
                acc = fmaf(c3row[q], t45[q * 32 + u], acc);
            Wl[e] = acc;
        }
        __syncthreads();
        // M2[i2][r][j] = sum_s c2l[r][s]*Wl[s][j]
#pragma unroll 4
        for (int k = 0; k < 16; ++k) {
            const int e = t + k * 256;
            const int r = e >> 7, j = e & 127;
            float acc = 0.f;
#pragma unroll
            for (int s = 0; s < 32; ++s)
                acc = fmaf(c2l[r * 32 + s], Wl[s * 128 + j], acc);
            M2[(i2 * 32 + r) * 128 + j] = acc;
        }
    } else if (b < NB_M2 + NB_G1T) {
        const int pair = (b - NB_M2) * 8 + (t >> 5);
        const int s = t & 31;
        const int i0 = pair / 100;
        const int i1 = pair - i0 * 100;
        const float4* a4 = (const float4*)(c0 + i0 * 32);
        const float* c1p = c1 + i1 * 32 + s;
        float acc = 0.f;
#pragma unroll
        for (int r4 = 0; r4 < 8; ++r4) {
            const float4 a = a4[r4];
            acc = fmaf(a.x, c1p[(r4 * 4 + 0) * 3200], acc);
            acc = fmaf(a.y, c1p[(r4 * 4 + 1) * 3200], acc);
            acc = fmaf(a.z, c1p[(r4 * 4 + 2) * 3200], acc);
            acc = fmaf(a.w, c1p[(r4 * 4 + 3) * 3200], acc);
        }
        G1T[pair * 32 + s] = acc;
    } else {
        const int hb = b - (NB_M2 + NB_G1T);
        int* lh = (int*)smem;
        if (t < 128) lh[t] = 0;
        __syncthreads();
#pragma unroll
        for (int k = 0; k < 4; ++k) {
            const int n = hb * 1024 + k * 256 + t;
            atomicAdd(&lh[idx[n] % 100], 1);
        }
        __syncthreads();
        if (t < 128) cnt[hb * 128 + t] = lh[t];   // plain store, no init needed
    }
}

// ---------------------------------------------------------------------------
// K2 "sort2" — 64 blocks; block j owns tokens [j*1024, j*1024+1024).
// Each block redundantly computes: totals, prefix-over-blocks offs_j, padded
// scan bases. Token slot = sb[b] + offs_j[b] + LDS-rank. Pad + tail = -1.
// No global atomics, no init, idempotent under graph replay.
// ---------------------------------------------------------------------------
__global__ __launch_bounds__(256) void sort2(const int* __restrict__ idx,
                                             const int* __restrict__ cnt,
                                             int* __restrict__ order) {
    __shared__ int cm[64 * 128];           // 32 KB
    __shared__ int totals[100];
    __shared__ int offsj[100];
    __shared__ int sb[101];
    __shared__ int lhj[100];
    const int j = blockIdx.x, t = threadIdx.x;
    {
        const int4* src = (const int4*)cnt;
        int4* dst = (int4*)cm;
#pragma unroll
        for (int k = 0; k < 8; ++k) dst[t + k * 256] = src[t + k * 256];
    }
    if (t < 100) lhj[t] = 0;
    __syncthreads();
    if (t < 100) {
        int tot = 0, off = 0;
        for (int hb = 0; hb < 64; ++hb) {
            const int c = cm[hb * 128 + t];
            if (hb < j) off += c;
            tot += c;
        }
        totals[t] = tot;
        offsj[t] = off;
    }
    __syncthreads();
    if (t < 64) {                          // wave 0: padded exclusive scan
        const int e0 = 2 * t, e1 = 2 * t + 1;
        const int p0 = (e0 < 100) ? ((totals[e0] + 127) & ~127) : 0;
        const int p1 = (e1 < 100) ? ((totals[e1] + 127) & ~127) : 0;
        const int pair = p0 + p1;
        int incl = pair;
#pragma unroll
        for (int d = 1; d < 64; d <<= 1) {
            const int v = __shfl_up(incl, d, 64);
            if (t >= d) incl += v;
        }
        const int base = incl - pair;
        if (e0 < 100) sb[e0] = base;
        if (e1 < 100) sb[e1] = base + p0;
        if (t == 63) sb[100] = incl;       // grand padded total
    }
    __syncthreads();
    // scatter own 1024 tokens
    int bkt[4], rnk[4];
#pragma unroll
    for (int k = 0; k < 4; ++k) {
        const int n = j * 1024 + k * 256 + t;
        const int bb = idx[n] % 100;
        bkt[k] = bb;
        rnk[k] = atomicAdd(&lhj[bb], 1);
    }
#pragma unroll
    for (int k = 0; k < 4; ++k) {
        const int n = j * 1024 + k * 256 + t;
        order[sb[bkt[k]] + offsj[bkt[k]] + rnk[k]] = n;
    }
    // pad-fill buckets b = j, j+64
    for (int bb = j; bb < 100; bb += 64) {
        const int tot = totals[bb];
        const int pt = (tot + 127) & ~127;
        for (int i = tot + t; i < pt; i += 256) order[sb[bb] + i] = -1;
    }
    // tail-fill [grand total, ORD_SIZE)
    {
        const int gt = sb[100];
        for (int i = gt + j * 256 + t; i < ORD_SIZE; i += 64 * 256) order[i] = -1;
    }
}

// ---------------------------------------------------------------------------
// K3: main  out[n][j] = sum_r G1T[iv/100][r] * M2[iv%100][r][j]   (verified)
// ---------------------------------------------------------------------------
__global__ __launch_bounds__(256) void tt_main(
    const int* __restrict__ idx, const int* __restrict__ order,
    const float* __restrict__ G1T, const float* __restrict__ M2,
    float* __restrict__ out) {
    __shared__ float M2l[32 * 128];
    __shared__ float g1l[32][132];
    __shared__ int   toks[TOKS_PER_BLK];

    const int t = threadIdx.x;
    const int base = blockIdx.x * TOKS_PER_BLK;
    const int n0 = order[base];
    if (n0 < 0) return;
    const int i2v = idx[n0] % 100;

    {
        const float4* src = (const float4*)(M2 + i2v * 4096);
        float4* dst = (float4*)M2l;
#pragma unroll
        for (int i = 0; i < 4; ++i) dst[t + i * 256] = src[t + i * 256];
    }
    {
        const int tk = t >> 1, half = t & 1;
        const int n = order[base + tk];
        float4 x0 = {0,0,0,0}, x1 = {0,0,0,0}, x2 = {0,0,0,0}, x3 = {0,0,0,0};
        if (n >= 0) {
            const int pair = idx[n] / 100;
            const float4* g = (const float4*)(G1T + pair * 32 + half * 16);
            x0 = g[0]; x1 = g[1]; x2 = g[2]; x3 = g[3];
        }
        const int rb = half * 16;
        g1l[rb +  0][tk] = x0.x; g1l[rb +  1][tk] = x0.y; g1l[rb +  2][tk] = x0.z; g1l[rb +  3][tk] = x0.w;
        g1l[rb +  4][tk] = x1.x; g1l[rb +  5][tk] = x1.y; g1l[rb +  6][tk] = x1.z; g1l[rb +  7][tk] = x1.w;
        g1l[rb +  8][tk] = x2.x; g1l[rb +  9][tk] = x2.y; g1l[rb + 10][tk] = x2.z; g1l[rb + 11][tk] = x2.w;
        g1l[rb + 12][tk] = x3.x; g1l[rb + 13][tk] = x3.y; g1l[rb + 14][tk] = x3.z; g1l[rb + 15][tk] = x3.w;
        if (t < TOKS_PER_BLK) toks[t] = order[base + t];
    }
    __syncthreads();

    const int tg = t >> 4;
    const int cg = t & 15;
    float4 acc[8][2];
#pragma unroll
    for (int k = 0; k < 8; ++k) {
        acc[k][0] = {0.f, 0.f, 0.f, 0.f};
        acc[k][1] = {0.f, 0.f, 0.f, 0.f};
    }

#pragma unroll 8
    for (int r = 0; r < 32; ++r) {
        const float* g1r = &g1l[r][tg * 8];
        const float4 ga = *(const float4*)g1r;
        const float4 gb = *(const float4*)(g1r + 4);
        const float4 m0 = *(const float4*)(M2l + r * 128 + cg * 4);
        const float4 m1 = *(const float4*)(M2l + r * 128 + 64 + cg * 4);
        FMA4(acc[0][0], ga.x, m0); FMA4(acc[0][1], ga.x, m1);
        FMA4(acc[1][0], ga.y, m0); FMA4(acc[1][1], ga.y, m1);
        FMA4(acc[2][0], ga.z, m0); FMA4(acc[2][1], ga.z, m1);
        FMA4(acc[3][0], ga.w, m0); FMA4(acc[3][1], ga.w, m1);
        FMA4(acc[4][0], gb.x, m0); FMA4(acc[4][1], gb.x, m1);
        FMA4(acc[5][0], gb.y, m0); FMA4(acc[5][1], gb.y, m1);
        FMA4(acc[6][0], gb.z, m0); FMA4(acc[6][1], gb.z, m1);
        FMA4(acc[7][0], gb.w, m0); FMA4(acc[7][1], gb.w, m1);
    }

#pragma unroll
    for (int k = 0; k < 8; ++k) {
        const int n = toks[tg * 8 + k];
        if (n >= 0) {
            float* o = out + (size_t)n * 128;
            *(float4*)(o + cg * 4)      = acc[k][0];
            *(float4*)(o + 64 + cg * 4) = acc[k][1];
        }
    }
}

// ---------------------------------------------------------------------------
// Fallback (round-4 verified) if ws too small.
// ---------------------------------------------------------------------------
__global__ void build_w(const float* __restrict__ c3, const float* __restrict__ c4,
                        const float* __restrict__ c5, float* __restrict__ W) {
    int t = blockIdx.x * blockDim.x + threadIdx.x;
    if (t >= 32 * 128) return;
    int r = t >> 7;
    int j = t & 127;
    int p  = j >> 5;
    int m1 = (j >> 2) & 7;
    int v  = j & 3;
    const float* c3row = c3 + (r * 4 + p) * 16;
    float acc = 0.f;
#pragma unroll
    for (int m2 = 0; m2 < 8; ++m2) {
        float t1 = 0.f;
#pragma unroll
        for (int q = 0; q < 16; ++q)
            t1 += c3row[q] * c4[q * 64 + m1 * 8 + m2];
        acc += t1 * c5[m2 * 4 + v];
    }
    W[r * 128 + j] = acc;
}

__global__ __launch_bounds__(256, 4) void tt_embed_fb(
    const int* __restrict__ idx, const float* __restrict__ c0,
    const float* __restrict__ c1, const float* __restrict__ c2,
    const float* __restrict__ Wg, float* __restrict__ out) {
    __shared__ float Wl[32 * 128];
    __shared__ float g2l[8][32];
    const int t = threadIdx.x;
    {
        const float4* Wg4 = (const float4*)Wg;
        float4* Wl4 = (float4*)Wl;
#pragma unroll
        for (int i = 0; i < 4; ++i) Wl4[t + i * 256] = Wg4[t + i * 256];
    }
    __syncthreads();
    const int tt = t >> 5, s = t & 31;
    const int blockBase = blockIdx.x * 32;
    for (int round = 0; round < 4; ++round) {
        const int n = blockBase + round * 8 + tt;
        const int iv = idx[n];
        const int i0 = iv / 10000;
        const int rem = iv - i0 * 10000;
        const int i1 = rem / 100;
        const int i2 = rem - i1 * 100;
        const float4* c0r4 = (const float4*)(c0 + i0 * 32);
        const float* c1p = c1 + i1 * 32 + s;
        float g1 = 0.f;
#pragma unroll
        for (int r4 = 0; r4 < 8; ++r4) {
            float4 a = c0r4[r4];
            g1 += a.x * c1p[(r4 * 4 + 0) * 3200];
            g1 += a.y * c1p[(r4 * 4 + 1) * 3200];
            g1 += a.z * c1p[(r4 * 4 + 2) * 3200];
            g1 += a.w * c1p[(r4 * 4 + 3) * 3200];
        }
        const float* c2p = c2 + i2 * 32 + s;
        float g2 = 0.f;
#pragma unroll
        for (int r = 0; r < 32; ++r) {
            float g1r = __shfl(g1, r, 32);
            g2 += g1r * c2p[r * 3200];
        }
        g2l[tt][s] = g2;
        __syncthreads();
        float4 acc = {0.f, 0.f, 0.f, 0.f};
        const float4* Wl4 = (const float4*)Wl;
#pragma unroll
        for (int r = 0; r < 32; ++r) {
            const float g = g2l[tt][r];
            const float4 w = Wl4[r * 32 + s];
            acc.x += g * w.x; acc.y += g * w.y; acc.z += g * w.z; acc.w += g * w.w;
        }
        float4* outp = (float4*)(out + (size_t)n * 128);
        outp[s] = acc;
        __syncthreads();
    }
}

// ---------------------------------------------------------------------------
extern "C" void kernel_launch(void* const* d_in, const int* in_sizes, int n_in,
                              void* d_out, int out_size, void* d_ws, size_t ws_size,
                              hipStream_t stream) {
    const int*   idx = (const int*)d_in[0];
    const float* c0  = (const float*)d_in[1];
    const float* c1  = (const float*)d_in[2];
    const float* c2  = (const float*)d_in[3];
    const float* c3  = (const float*)d_in[4];
    const float* c4  = (const float*)d_in[5];
    const float* c5  = (const float*)d_in[6];
    float* out = (float*)d_out;
    float* ws  = (float*)d_ws;

    if (ws_size >= WS_NEED) {
        float* M2  = ws + WS_M2;
        float* G1T = ws + WS_G1T;
        int* cnt   = (int*)(ws + WS_CNT);
        int* order = (int*)(ws + WS_ORD);

        hipLaunchKernelGGL(prep,  dim3(PREP_BLOCKS), dim3(256), 0, stream,
                           idx, c0, c1, c2, c3, c4, c5, M2, G1T, cnt);
        hipLaunchKernelGGL(sort2, dim3(NB_HIST), dim3(256), 0, stream, idx, cnt, order);
        hipLaunchKernelGGL(tt_main, dim3(MAIN_BLOCKS), dim3(256), 0, stream,
                           idx, order, G1T, M2, out);
    } else {
        float* W = ws;
        hipLaunchKernelGGL(build_w, dim3(16), dim3(256), 0, stream, c3, c4, c5, W);
        hipLaunchKernelGGL(tt_embed_fb, dim3(N_TOKENS / 32), dim3(256), 0, stream,
                           idx, c0, c1, c2, W, out);
    }
}

// Round 10
// 30.049 us; speedup vs baseline: 3.8321x; 1.1389x over previous
//
#include <hip/hip_runtime.h>

#define N_TOKENS   65536
#define TOKS_PER_BLK 128
#define MAIN_TILES (N_TOKENS / TOKS_PER_BLK + 100)    // 612
#define ORD_SIZE    (MAIN_TILES * TOKS_PER_BLK)       // 78336
#define NB_M2   100
#define NB_G1T  1250
#define NB_HIST 64
#define PREP_BLOCKS (NB_M2 + NB_G1T + NB_HIST)        // 1414

// ---- ws layout (float offsets) ----
#define WS_M2T  0                          // 100*4096 bf16 = 204800 floats
#define WS_G1T  204800                     // 10000*32 bf16 = 160000 floats
#define WS_CNT  364800                     // 64*128 ints
#define WS_ORD  372992                     // ORD_SIZE ints
#define WS_NEED ((size_t)(372992 + ORD_SIZE) * 4)     // ~1.8 MB

typedef __attribute__((ext_vector_type(8))) short bf16x8;
typedef __attribute__((ext_vector_type(4))) float f32x4;

__device__ __forceinline__ unsigned short f2bf(float x) {
    union { float f; unsigned u; } v; v.f = x;
    unsigned r = v.u + 0x7FFF + ((v.u >> 16) & 1);   // RNE
    return (unsigned short)(r >> 16);
}

// ---------------------------------------------------------------------------
// K1 "prep" — role-split by blockIdx.x:
//   [0,100):      per-i2 W (in LDS) + M2T[i2][j][r] (bf16, k-contiguous)
//   [100,1350):   G1Tb[pair][s] bf16
//   [1350,1414):  per-block hist of i2 -> cnt (plain stores)
// ---------------------------------------------------------------------------
__global__ __launch_bounds__(256) void prep(
    const int* __restrict__ idx,
    const float* __restrict__ c0, const float* __restrict__ c1,
    const float* __restrict__ c2, const float* __restrict__ c3,
    const float* __restrict__ c4, const float* __restrict__ c5,
    unsigned short* __restrict__ M2T, unsigned short* __restrict__ G1Tb,
    int* __restrict__ cnt) {
    __shared__ float smem[8768];           // 34.3 KB union buffer
    const int b = blockIdx.x, t = threadIdx.x;

    if (b < NB_M2) {
        const int i2 = b;
        float* c4l = smem;                 // 1024
        float* c5l = smem + 1024;          // 32
        float* t45 = smem + 1056;          // 512
        float* c3l = smem + 1568;          // 2048
        float* Wl  = smem + 3616;          // 4096
        float* c2l = smem + 7712;          // 32x33 = 1056 (stride 33: conflict-free col reads)
        *(float4*)(c4l + t * 4) = *(const float4*)(c4 + t * 4);
        if (t < 8) *(float4*)(c5l + t * 4) = *(const float4*)(c5 + t * 4);
        *(float4*)(c3l + t * 8)     = *(const float4*)(c3 + t * 8);
        *(float4*)(c3l + t * 8 + 4) = *(const float4*)(c3 + t * 8 + 4);
        {
            const int r = t >> 3, s4 = (t & 7) * 4;
            const float4 v = *(const float4*)(c2 + r * 3200 + i2 * 32 + s4);
            c2l[r * 33 + s4 + 0] = v.x;
            c2l[r * 33 + s4 + 1] = v.y;
            c2l[r * 33 + s4 + 2] = v.z;
            c2l[r * 33 + s4 + 3] = v.w;
        }
        __syncthreads();
#pragma unroll
        for (int k = 0; k < 2; ++k) {      // T45[q][u] = sum_m2 c4[q,m1,m2]*c5[m2,v]
            const int e = t + k * 256;
            const int q = e >> 5, u = e & 31;
            const int m1 = u >> 2, v = u & 3;
            float acc = 0.f;
#pragma unroll
            for (int m2 = 0; m2 < 8; ++m2)
                acc = fmaf(c4l[q * 64 + m1 * 8 + m2], c5l[m2 * 4 + v], acc);
            t45[e] = acc;
        }
        __syncthreads();
#pragma unroll 4
        for (int k = 0; k < 16; ++k) {     // W[r][j] = sum_q c3[r,p,q]*T45[q][u]
            const int e = t + k * 256;
            const int r = e >> 7, j = e & 127;
            const int p = j >> 5, u = j & 31;
            const float* c3row = c3l + (r * 4 + p) * 16;
            float acc = 0.f;
#pragma unroll
            for (int q = 0; q < 16; ++q)
                acc = fmaf(c3row[q], t45[q * 32 + u], acc);
            Wl[e] = acc;
        }
        __syncthreads();
        // M2T[i2][j*32 + r] = bf16( sum_s c2[r,i2,s] * W[s,j] )
#pragma unroll 4
        for (int k = 0; k < 16; ++k) {
            const int e = t + k * 256;     // e = j*32 + r
            const int j = e >> 5, r = e & 31;
            float acc = 0.f;
#pragma unroll
            for (int s = 0; s < 32; ++s)
                acc = fmaf(c2l[r * 33 + s], Wl[s * 128 + j], acc);
            M2T[i2 * 4096 + e] = f2bf(acc);
        }
    } else if (b < NB_M2 + NB_G1T) {
        const int pair = (b - NB_M2) * 8 + (t >> 5);
        const int s = t & 31;
        const int i0 = pair / 100;
        const int i1 = pair - i0 * 100;
        const float4* a4 = (const float4*)(c0 + i0 * 32);
        const float* c1p = c1 + i1 * 32 + s;
        float acc = 0.f;
#pragma unroll
        for (int r4 = 0; r4 < 8; ++r4) {
            const float4 a = a4[r4];
            acc = fmaf(a.x, c1p[(r4 * 4 + 0) * 3200], acc);
            acc = fmaf(a.y, c1p[(r4 * 4 + 1) * 3200], acc);
            acc = fmaf(a.z, c1p[(r4 * 4 + 2) * 3200], acc);
            acc = fmaf(a.w, c1p[(r4 * 4 + 3) * 3200], acc);
        }
        G1Tb[pair * 32 + s] = f2bf(acc);
    } else {
        const int hb = b - (NB_M2 + NB_G1T);
        int* lh = (int*)smem;
        if (t < 128) lh[t] = 0;
        __syncthreads();
#pragma unroll
        for (int k = 0; k < 4; ++k) {
            const int n = hb * 1024 + k * 256 + t;
            atomicAdd(&lh[idx[n] % 100], 1);
        }
        __syncthreads();
        if (t < 128) cnt[hb * 128 + t] = lh[t];
    }
}

// ---------------------------------------------------------------------------
// K2 "sort2" — verbatim round-8 (verified): deterministic bucket sort.
// ---------------------------------------------------------------------------
__global__ __launch_bounds__(256) void sort2(const int* __restrict__ idx,
                                             const int* __restrict__ cnt,
                                             int* __restrict__ order) {
    __shared__ int cm[64 * 128];
    __shared__ int totals[100];
    __shared__ int offsj[100];
    __shared__ int sb[101];
    __shared__ int lhj[100];
    const int j = blockIdx.x, t = threadIdx.x;
    {
        const int4* src = (const int4*)cnt;
        int4* dst = (int4*)cm;
#pragma unroll
        for (int k = 0; k < 8; ++k) dst[t + k * 256] = src[t + k * 256];
    }
    if (t < 100) lhj[t] = 0;
    __syncthreads();
    if (t < 100) {
        int tot = 0, off = 0;
        for (int hb = 0; hb < 64; ++hb) {
            const int c = cm[hb * 128 + t];
            if (hb < j) off += c;
            tot += c;
        }
        totals[t] = tot;
        offsj[t] = off;
    }
    __syncthreads();
    if (t < 64) {
        const int e0 = 2 * t, e1 = 2 * t + 1;
        const int p0 = (e0 < 100) ? ((totals[e0] + 127) & ~127) : 0;
        const int p1 = (e1 < 100) ? ((totals[e1] + 127) & ~127) : 0;
        const int pair = p0 + p1;
        int incl = pair;
#pragma unroll
        for (int d = 1; d < 64; d <<= 1) {
            const int v = __shfl_up(incl, d, 64);
            if (t >= d) incl += v;
        }
        const int base = incl - pair;
        if (e0 < 100) sb[e0] = base;
        if (e1 < 100) sb[e1] = base + p0;
        if (t == 63) sb[100] = incl;
    }
    __syncthreads();
    int bkt[4], rnk[4];
#pragma unroll
    for (int k = 0; k < 4; ++k) {
        const int n = j * 1024 + k * 256 + t;
        const int bb = idx[n] % 100;
        bkt[k] = bb;
        rnk[k] = atomicAdd(&lhj[bb], 1);
    }
#pragma unroll
    for (int k = 0; k < 4; ++k) {
        const int n = j * 1024 + k * 256 + t;
        order[sb[bkt[k]] + offsj[bkt[k]] + rnk[k]] = n;
    }
    for (int bb = j; bb < 100; bb += 64) {
        const int tot = totals[bb];
        const int pt = (tot + 127) & ~127;
        for (int i = tot + t; i < pt; i += 256) order[sb[bb] + i] = -1;
    }
    {
        const int gt = sb[100];
        for (int i = gt + j * 256 + t; i < ORD_SIZE; i += 64 * 256) order[i] = -1;
    }
}

// ---------------------------------------------------------------------------
// K3 "tt_main" — MFMA version. Per block: out[128 tok][128 col] =
// G1[128x32] @ M2[32x128], via 64 x mfma_f32_16x16x32_bf16 (16/wave).
// LDS: g1b[tok][k], m2t[j][k], both stride 40 shorts (2-way-max banks).
// A-frag: row=lane&15, k=(lane>>4)*8+e (contig).  B-frag: col=lane&15, same k.
// C/D:    col=lane&15, row=4*(lane>>4)+reg  [verified m89].
// ---------------------------------------------------------------------------
__global__ __launch_bounds__(256) void tt_main(
    const int* __restrict__ idx, const int* __restrict__ order,
    const unsigned short* __restrict__ G1Tb, const unsigned short* __restrict__ M2T,
    float* __restrict__ out) {
    __shared__ unsigned short g1b[128 * 40];   // 10.2 KB
    __shared__ unsigned short m2t[128 * 40];   // 10.2 KB
    __shared__ int toks[TOKS_PER_BLK];

    const int t = threadIdx.x;
    const int base = blockIdx.x * TOKS_PER_BLK;
    const int n0 = order[base];
    if (n0 < 0) return;
    const int i2v = idx[n0] % 100;

    // stage g1 rows (bf16, 64B each): 2 threads/token
    {
        const int tk = t >> 1, half = t & 1;
        const int n = order[base + tk];
        int4 v0 = {0, 0, 0, 0}, v1 = {0, 0, 0, 0};
        if (n >= 0) {
            const int pair = idx[n] / 100;
            const int4* g = (const int4*)(G1Tb + pair * 32);
            v0 = g[half * 2];
            v1 = g[half * 2 + 1];
        }
        int4* d = (int4*)(g1b + tk * 40 + half * 16);
        d[0] = v0;
        d[1] = v1;
        if (t < TOKS_PER_BLK) toks[t] = order[base + t];
    }
    // stage M2T slice (8 KB): 2 threads/row
    {
        const int j = t >> 1, half = t & 1;
        const int4* s = (const int4*)(M2T + i2v * 4096 + j * 32);
        int4* d = (int4*)(m2t + j * 40 + half * 16);
        d[0] = s[half * 2];
        d[1] = s[half * 2 + 1];
    }
    __syncthreads();

    const int wid  = t >> 6;
    const int lane = t & 63;
    const int ln15 = lane & 15;
    const int q8   = (lane >> 4) * 8;

    f32x4 acc[2][8];
#pragma unroll
    for (int a = 0; a < 2; ++a)
#pragma unroll
        for (int c = 0; c < 8; ++c) acc[a][c] = (f32x4){0.f, 0.f, 0.f, 0.f};

    bf16x8 af[2], bf[8];
#pragma unroll
    for (int trr = 0; trr < 2; ++trr) {
        const int tok = (2 * wid + trr) * 16 + ln15;
        af[trr] = *(const bf16x8*)(g1b + tok * 40 + q8);
    }
#pragma unroll
    for (int tc = 0; tc < 8; ++tc) {
        const int j = tc * 16 + ln15;
        bf[tc] = *(const bf16x8*)(m2t + j * 40 + q8);
    }
#pragma unroll
    for (int trr = 0; trr < 2; ++trr)
#pragma unroll
        for (int tc = 0; tc < 8; ++tc)
            acc[trr][tc] = __builtin_amdgcn_mfma_f32_16x16x32_bf16(
                af[trr], bf[tc], acc[trr][tc], 0, 0, 0);

    const int rowq = (lane >> 4) * 4;
#pragma unroll
    for (int trr = 0; trr < 2; ++trr) {
#pragma unroll
        for (int reg = 0; reg < 4; ++reg) {
            const int tokr = (2 * wid + trr) * 16 + rowq + reg;
            const int n = toks[tokr];
            if (n >= 0) {
                float* o = out + (size_t)n * 128 + ln15;
#pragma unroll
                for (int tc = 0; tc < 8; ++tc) o[tc * 16] = acc[trr][tc][reg];
            }
        }
    }
}

// ---------------------------------------------------------------------------
// Fallback (round-4 verified) if ws too small.
// ---------------------------------------------------------------------------
__global__ void build_w(const float* __restrict__ c3, const float* __restrict__ c4,
                        const float* __restrict__ c5, float* __restrict__ W) {
    int t = blockIdx.x * blockDim.x + threadIdx.x;
    if (t >= 32 * 128) return;
    int r = t >> 7;
    int j = t & 127;
    int p  = j >> 5;
    int m1 = (j >> 2) & 7;
    int v  = j & 3;
    const float* c3row = c3 + (r * 4 + p) * 16;
    float acc = 0.f;
#pragma unroll
    for (int m2 = 0; m2 < 8; ++m2) {
        float t1 = 0.f;
#pragma unroll
        for (int q = 0; q < 16; ++q)
            t1 += c3row[q] * c4[q * 64 + m1 * 8 + m2];
        acc += t1 * c5[m2 * 4 + v];
    }
    W[r * 128 + j] = acc;
}

__global__ __launch_bounds__(256, 4) void tt_embed_fb(
    const int* __restrict__ idx, const float* __restrict__ c0,
    const float* __restrict__ c1, const float* __restrict__ c2,
    const float* __restrict__ Wg, float* __restrict__ out) {
    __shared__ float Wl[32 * 128];
    __shared__ float g2l[8][32];
    const int t = threadIdx.x;
    {
        const float4* Wg4 = (const float4*)Wg;
        float4* Wl4 = (float4*)Wl;
#pragma unroll
        for (int i = 0; i < 4; ++i) Wl4[t + i * 256] = Wg4[t + i * 256];
    }
    __syncthreads();
    const int tt = t >> 5, s = t & 31;
    const int blockBase = blockIdx.x * 32;
    for (int round = 0; round < 4; ++round) {
        const int n = blockBase + round * 8 + tt;
        const int iv = idx[n];
        const int i0 = iv / 10000;
        const int rem = iv - i0 * 10000;
        const int i1 = rem / 100;
        const int i2 = rem - i1 * 100;
        const float4* c0r4 = (const float4*)(c0 + i0 * 32);
        const float* c1p = c1 + i1 * 32 + s;
        float g1 = 0.f;
#pragma unroll
        for (int r4 = 0; r4 < 8; ++r4) {
            float4 a = c0r4[r4];
            g1 += a.x * c1p[(r4 * 4 + 0) * 3200];
            g1 += a.y * c1p[(r4 * 4 + 1) * 3200];
            g1 += a.z * c1p[(r4 * 4 + 2) * 3200];
            g1 += a.w * c1p[(r4 * 4 + 3) * 3200];
        }
        const float* c2p = c2 + i2 * 32 + s;
        float g2 = 0.f;
#pragma unroll
        for (int r = 0; r < 32; ++r) {
            float g1r = __shfl(g1, r, 32);
            g2 += g1r * c2p[r * 3200];
        }
        g2l[tt][s] = g2;
        __syncthreads();
        float4 acc = {0.f, 0.f, 0.f, 0.f};
        const float4* Wl4 = (const float4*)Wl;
#pragma unroll
        for (int r = 0; r < 32; ++r) {
            const float g = g2l[tt][r];
            const float4 w = Wl4[r * 32 + s];
            acc.x += g * w.x; acc.y += g * w.y; acc.z += g * w.z; acc.w += g * w.w;
        }
        float4* outp = (float4*)(out + (size_t)n * 128);
        outp[s] = acc;
        __syncthreads();
    }
}

// ---------------------------------------------------------------------------
extern "C" void kernel_launch(void* const* d_in, const int* in_sizes, int n_in,
                              void* d_out, int out_size, void* d_ws, size_t ws_size,
                              hipStream_t stream) {
    const int*   idx = (const int*)d_in[0];
    const float* c0  = (const float*)d_in[1];
    const float* c1  = (const float*)d_in[2];
    const float* c2  = (const float*)d_in[3];
    const float* c3  = (const float*)d_in[4];
    const float* c4  = (const float*)d_in[5];
    const float* c5  = (const float*)d_in[6];
    float* out = (float*)d_out;
    float* ws  = (float*)d_ws;

    if (ws_size >= WS_NEED) {
        unsigned short* M2T  = (unsigned short*)(ws + WS_M2T);
        unsigned short* G1Tb = (unsigned short*)(ws + WS_G1T);
        int* cnt   = (int*)(ws + WS_CNT);
        int* order = (int*)(ws + WS_ORD);

        hipLaunchKernelGGL(prep,  dim3(PREP_BLOCKS), dim3(256), 0, stream,
                           idx, c0, c1, c2, c3, c4, c5, M2T, G1Tb, cnt);
        hipLaunchKernelGGL(sort2, dim3(NB_HIST), dim3(256), 0, stream, idx, cnt, order);
        hipLaunchKernelGGL(tt_main, dim3(MAIN_TILES), dim3(256), 0, stream,
                           idx, order, G1Tb, M2T, out);
    } else {
        float* W = ws;
        hipLaunchKernelGGL(build_w, dim3(16), dim3(256), 0, stream, c3, c4, c5, W);
        hipLaunchKernelGGL(tt_embed_fb, dim3(N_TOKENS / 32), dim3(256), 0, stream,
                           idx, c0, c1, c2, W, out);
    }
}